// Round 7
// baseline (747.980 us; speedup 1.0000x reference)
//
#include <hip/hip_runtime.h>
#include <hip/hip_bf16.h>

// ---------------------------------------------------------------------------
// R7: hi/lo pass-split staging (halves conv LDS -> 6 blocks/CU), depth-3
// rolling weight prefetch in decoder kernels, launch fusion (26 -> 15).
// ---------------------------------------------------------------------------

typedef __attribute__((ext_vector_type(8))) short bf16x8;   // 8 bf16 = 4 VGPRs
typedef __attribute__((ext_vector_type(4))) float f32x4;

static __device__ __forceinline__ unsigned short f2bf(float f) {
    __hip_bfloat16 h = __float2bfloat16(f);
    return *reinterpret_cast<unsigned short*>(&h);
}
static __device__ __forceinline__ float bf2f(unsigned short u) {
    return __uint_as_float(((unsigned int)u) << 16);
}

// ===================== conv1: fp32 direct, split NHWC output ===============
__global__ __launch_bounds__(256)
void conv1_kernel(const float* __restrict__ in, const float* __restrict__ W,
                  const float* __restrict__ Bias,
                  unsigned short* __restrict__ out_hi,
                  unsigned short* __restrict__ out_lo)
{
    constexpr int R = 17, C = 17;
    __shared__ float ilds[3*R*C];
    __shared__ float wlds[27*32];
    const int n = blockIdx.z, co0 = blockIdx.y*32;
    const int ty = blockIdx.x >> 3, tx = blockIdx.x & 7;
    const int oh0 = ty*8, ow0 = tx*8;
    const int t = threadIdx.x, p = t & 63, grp = t >> 6;
    const int py = p >> 3, px = p & 7;
    const int r0 = 2*oh0, c0 = 2*ow0;

    const float* ibase = in + (long)n*3*16384;
    for (int idx = t; idx < 3*R*C; idx += 256) {
        int ck = idx/(R*C), rc = idx%(R*C);
        int r = rc/C, c = rc%C;
        int ih = r0+r, iw = c0+c;
        float v = 0.f;
        if (ih < 128 && iw < 128) v = ibase[ck*16384 + ih*128 + iw];
        ilds[idx] = v;
    }
    for (int idx = t; idx < 32*27; idx += 256) {
        int co = idx & 31, rem = idx >> 5;
        wlds[rem*32 + co] = W[(co0+co)*27 + rem];
    }
    __syncthreads();

    float acc[8];
    #pragma unroll
    for (int i=0;i<8;i++) acc[i]=0.f;

    #pragma unroll
    for (int ck = 0; ck < 3; ++ck) {
        float xv[9];
        #pragma unroll
        for (int kh = 0; kh < 3; ++kh)
            #pragma unroll
            for (int kw = 0; kw < 3; ++kw)
                xv[kh*3+kw] = ilds[ck*289 + (2*py+kh)*17 + 2*px+kw];
        #pragma unroll
        for (int k = 0; k < 9; ++k) {
            #pragma unroll
            for (int g = 0; g < 2; ++g) {
                const float4 w = *reinterpret_cast<const float4*>(
                    &wlds[(ck*9+k)*32 + grp*8 + g*4]);
                acc[g*4+0] += xv[k]*w.x;
                acc[g*4+1] += xv[k]*w.y;
                acc[g*4+2] += xv[k]*w.z;
                acc[g*4+3] += xv[k]*w.w;
            }
        }
    }

    const long obase = (((long)n*64 + oh0+py)*64 + ow0+px)*64 + co0 + grp*8;
    #pragma unroll
    for (int g = 0; g < 2; ++g) {
        ushort4 sh, sl;
        #pragma unroll
        for (int j = 0; j < 4; ++j) {
            int co = co0 + grp*8 + g*4 + j;
            float v = fmaxf(acc[g*4+j] + Bias[co], 0.f);
            unsigned short h = f2bf(v);
            ((unsigned short*)&sh)[j] = h;
            ((unsigned short*)&sl)[j] = f2bf(v - bf2f(h));
        }
        *reinterpret_cast<ushort4*>(&out_hi[obase + g*4]) = sh;
        *reinterpret_cast<ushort4*>(&out_lo[obase + g*4]) = sl;
    }
}

// ===================== split-bf16 MFMA stride-2 conv v3 (conv2-4) ==========
// Single LDS buffer (23.3 KB): pass A stages x_hi (taps: ah*b + al*b),
// pass B restages with x_lo (taps: ah*b).  Wave tile 64co x 64px.
template<int CI,int CO,int HO,int NW>
__global__ __launch_bounds__(NW*64, 2)
void bb_conv_v3(const unsigned short* __restrict__ in_hi,
                const unsigned short* __restrict__ in_lo,
                const unsigned short* __restrict__ Whi,
                const unsigned short* __restrict__ Wlo,
                const float* __restrict__ Bias,
                unsigned short* __restrict__ out_hi,
                unsigned short* __restrict__ out_lo)
{
    constexpr int HI = HO*2;
    constexpr int R = 17, C = 17;          // input tile for 8x8 out, stride 2
    constexpr int CK = 32, PITCH = 40;
    constexpr int NTHR = NW*64;

    __shared__ __align__(16) unsigned short xlds[R*C*PITCH];

    const int n   = blockIdx.z;
    const int co0 = blockIdx.y * (NW*64);
    constexpr int TILES_X = HO/8;
    const int ty = blockIdx.x / TILES_X, tx = blockIdx.x % TILES_X;
    const int oh0 = ty*8, ow0 = tx*8;
    const int r0 = 2*oh0, c0 = 2*ow0;

    const int t = threadIdx.x;
    const int w = t >> 6, lane = t & 63;
    const int s = lane & 15, q = lane >> 4;

    int dyy[4], dxx[4];
    #pragma unroll
    for (int si = 0; si < 4; ++si) { dyy[si] = si*2 + (s>>3); dxx[si] = s & 7; }

    const unsigned short* inHn = in_hi + (long)n*HI*HI*CI;
    const unsigned short* inLn = in_lo + (long)n*HI*HI*CI;

    int wrow[4];
    #pragma unroll
    for (int tn = 0; tn < 4; ++tn)
        wrow[tn] = (co0 + w*64 + tn*16 + s)*9*CI + q*8;

    f32x4 acc[4][4];
    #pragma unroll
    for (int si = 0; si < 4; ++si)
        #pragma unroll
        for (int tn = 0; tn < 4; ++tn)
            acc[si][tn] = (f32x4){0.f,0.f,0.f,0.f};

    auto stage = [&](const unsigned short* base, int ci0) {
        for (int i8 = t; i8 < R*C*4; i8 += NTHR) {
            int pix = i8 >> 2, cs = i8 & 3;
            int r = pix / C, c = pix % C;
            int ih = r0 + r, iw = c0 + c;
            uint4 v = {0u,0u,0u,0u};
            if (ih < HI && iw < HI)
                v = *reinterpret_cast<const uint4*>(&base[((long)ih*HI + iw)*CI + ci0 + cs*8]);
            *reinterpret_cast<uint4*>(&xlds[pix*PITCH + cs*8]) = v;
        }
    };

    for (int ci0 = 0; ci0 < CI; ci0 += CK) {
        // ===== pass A: x_hi =====
        stage(inHn, ci0);
        __syncthreads();
        {
            bf16x8 ah[2][4], al[2][4];
            #pragma unroll
            for (int tn = 0; tn < 4; ++tn) {
                ah[0][tn] = *reinterpret_cast<const bf16x8*>(&Whi[wrow[tn] + ci0]);
                al[0][tn] = *reinterpret_cast<const bf16x8*>(&Wlo[wrow[tn] + ci0]);
            }
            #pragma unroll
            for (int k = 0; k < 9; ++k) {
                const int cur = k & 1, nxt = cur ^ 1;
                if (k < 8) {
                    #pragma unroll
                    for (int tn = 0; tn < 4; ++tn) {
                        ah[nxt][tn] = *reinterpret_cast<const bf16x8*>(&Whi[wrow[tn] + (k+1)*CI + ci0]);
                        al[nxt][tn] = *reinterpret_cast<const bf16x8*>(&Wlo[wrow[tn] + (k+1)*CI + ci0]);
                    }
                }
                const int kh = k/3, kw = k%3;
                #pragma unroll
                for (int si = 0; si < 4; ++si) {
                    bf16x8 b = *reinterpret_cast<const bf16x8*>(
                        &xlds[((2*dyy[si]+kh)*C + 2*dxx[si]+kw)*PITCH + q*8]);
                    #pragma unroll
                    for (int tn = 0; tn < 4; ++tn) {
                        acc[si][tn] = __builtin_amdgcn_mfma_f32_16x16x32_bf16(ah[cur][tn], b, acc[si][tn], 0,0,0);
                        acc[si][tn] = __builtin_amdgcn_mfma_f32_16x16x32_bf16(al[cur][tn], b, acc[si][tn], 0,0,0);
                    }
                }
            }
        }
        __syncthreads();
        // ===== pass B: x_lo =====
        stage(inLn, ci0);
        __syncthreads();
        {
            bf16x8 a2[2][4];
            #pragma unroll
            for (int tn = 0; tn < 4; ++tn)
                a2[0][tn] = *reinterpret_cast<const bf16x8*>(&Whi[wrow[tn] + ci0]);
            #pragma unroll
            for (int k = 0; k < 9; ++k) {
                const int cur = k & 1, nxt = cur ^ 1;
                if (k < 8) {
                    #pragma unroll
                    for (int tn = 0; tn < 4; ++tn)
                        a2[nxt][tn] = *reinterpret_cast<const bf16x8*>(&Whi[wrow[tn] + (k+1)*CI + ci0]);
                }
                const int kh = k/3, kw = k%3;
                #pragma unroll
                for (int si = 0; si < 4; ++si) {
                    bf16x8 b = *reinterpret_cast<const bf16x8*>(
                        &xlds[((2*dyy[si]+kh)*C + 2*dxx[si]+kw)*PITCH + q*8]);
                    #pragma unroll
                    for (int tn = 0; tn < 4; ++tn)
                        acc[si][tn] = __builtin_amdgcn_mfma_f32_16x16x32_bf16(a2[cur][tn], b, acc[si][tn], 0,0,0);
                }
            }
        }
        __syncthreads();
    }

    #pragma unroll
    for (int si = 0; si < 4; ++si) {
        const int oh = oh0 + dyy[si], ow = ow0 + dxx[si];
        #pragma unroll
        for (int tn = 0; tn < 4; ++tn) {
            int co_b = co0 + w*64 + tn*16 + q*4;
            ushort4 sh, sl;
            #pragma unroll
            for (int r = 0; r < 4; ++r) {
                float v = fmaxf(acc[si][tn][r] + Bias[co_b + r], 0.f);
                unsigned short h = f2bf(v);
                ((unsigned short*)&sh)[r] = h;
                ((unsigned short*)&sl)[r] = f2bf(v - bf2f(h));
            }
            long ob = (((long)n*HO + oh)*HO + ow)*CO + co_b;
            *reinterpret_cast<ushort4*>(&out_hi[ob]) = sh;
            *reinterpret_cast<ushort4*>(&out_lo[ob]) = sl;
        }
    }
}

// ===================== conv5: 8-way ci-split partial + reduce ==============
__global__ __launch_bounds__(128, 2)
void conv5_partial(const unsigned short* __restrict__ in_hi,
                   const unsigned short* __restrict__ in_lo,
                   const unsigned short* __restrict__ Whi,
                   const unsigned short* __restrict__ Wlo,
                   float* __restrict__ skbuf)
{
    constexpr int CI = 512, HI = 8;
    constexpr int R = 9, C = 9, CK = 32, PITCH = 40;

    __shared__ __align__(16) unsigned short xlds[4*R*C*PITCH];   // 25.9 KB

    const int sk  = blockIdx.x;
    const int co0 = blockIdx.y * 128;
    const int n0  = blockIdx.z * 4;
    const int t = threadIdx.x;
    const int w = t >> 6, lane = t & 63;
    const int s = lane & 15, q = lane >> 4;
    const int dyy = s >> 2, dxx = s & 3;

    int wrow[4];
    #pragma unroll
    for (int tn = 0; tn < 4; ++tn)
        wrow[tn] = (co0 + w*64 + tn*16 + s)*9*CI + q*8;

    f32x4 acc[4][4];
    #pragma unroll
    for (int si = 0; si < 4; ++si)
        #pragma unroll
        for (int tn = 0; tn < 4; ++tn)
            acc[si][tn] = (f32x4){0.f,0.f,0.f,0.f};

    auto stage = [&](const unsigned short* base, int ci0) {
        for (int i8 = t; i8 < 4*324; i8 += 128) {
            int ti = i8 / 324, rem = i8 % 324;
            int pix = rem >> 2, cs = rem & 3;
            int r = pix / C, c = pix % C;
            uint4 v = {0u,0u,0u,0u};
            if (r < HI && c < HI)
                v = *reinterpret_cast<const uint4*>(
                    &base[(((long)(n0+ti)*HI + r)*HI + c)*CI + ci0 + cs*8]);
            *reinterpret_cast<uint4*>(&xlds[(ti*R*C + pix)*PITCH + cs*8]) = v;
        }
    };

    for (int cc = 0; cc < 64; cc += CK) {
        const int ci0 = sk*64 + cc;
        // pass A: x_hi
        stage(in_hi, ci0);
        __syncthreads();
        {
            bf16x8 ah[2][4], al[2][4];
            #pragma unroll
            for (int tn = 0; tn < 4; ++tn) {
                ah[0][tn] = *reinterpret_cast<const bf16x8*>(&Whi[wrow[tn] + ci0]);
                al[0][tn] = *reinterpret_cast<const bf16x8*>(&Wlo[wrow[tn] + ci0]);
            }
            #pragma unroll
            for (int k = 0; k < 9; ++k) {
                const int cur = k & 1, nxt = cur ^ 1;
                if (k < 8) {
                    #pragma unroll
                    for (int tn = 0; tn < 4; ++tn) {
                        ah[nxt][tn] = *reinterpret_cast<const bf16x8*>(&Whi[wrow[tn] + (k+1)*CI + ci0]);
                        al[nxt][tn] = *reinterpret_cast<const bf16x8*>(&Wlo[wrow[tn] + (k+1)*CI + ci0]);
                    }
                }
                const int kh = k/3, kw = k%3;
                #pragma unroll
                for (int si = 0; si < 4; ++si) {
                    bf16x8 b = *reinterpret_cast<const bf16x8*>(
                        &xlds[(si*R*C + (2*dyy+kh)*C + 2*dxx+kw)*PITCH + q*8]);
                    #pragma unroll
                    for (int tn = 0; tn < 4; ++tn) {
                        acc[si][tn] = __builtin_amdgcn_mfma_f32_16x16x32_bf16(ah[cur][tn], b, acc[si][tn], 0,0,0);
                        acc[si][tn] = __builtin_amdgcn_mfma_f32_16x16x32_bf16(al[cur][tn], b, acc[si][tn], 0,0,0);
                    }
                }
            }
        }
        __syncthreads();
        // pass B: x_lo
        stage(in_lo, ci0);
        __syncthreads();
        {
            bf16x8 a2[2][4];
            #pragma unroll
            for (int tn = 0; tn < 4; ++tn)
                a2[0][tn] = *reinterpret_cast<const bf16x8*>(&Whi[wrow[tn] + ci0]);
            #pragma unroll
            for (int k = 0; k < 9; ++k) {
                const int cur = k & 1, nxt = cur ^ 1;
                if (k < 8) {
                    #pragma unroll
                    for (int tn = 0; tn < 4; ++tn)
                        a2[nxt][tn] = *reinterpret_cast<const bf16x8*>(&Whi[wrow[tn] + (k+1)*CI + ci0]);
                }
                const int kh = k/3, kw = k%3;
                #pragma unroll
                for (int si = 0; si < 4; ++si) {
                    bf16x8 b = *reinterpret_cast<const bf16x8*>(
                        &xlds[(si*R*C + (2*dyy+kh)*C + 2*dxx+kw)*PITCH + q*8]);
                    #pragma unroll
                    for (int tn = 0; tn < 4; ++tn)
                        acc[si][tn] = __builtin_amdgcn_mfma_f32_16x16x32_bf16(a2[cur][tn], b, acc[si][tn], 0,0,0);
                }
            }
        }
        __syncthreads();
    }

    #pragma unroll
    for (int si = 0; si < 4; ++si) {
        #pragma unroll
        for (int tn = 0; tn < 4; ++tn) {
            int co_b = co0 + w*64 + tn*16 + q*4;
            long o = (((long)sk*64 + n0+si)*16 + s)*512 + co_b;
            *reinterpret_cast<f32x4*>(&skbuf[o]) = acc[si][tn];
        }
    }
}

__global__ __launch_bounds__(256)
void conv5_reduce(const float* __restrict__ skbuf, const float* __restrict__ Bias,
                  unsigned short* __restrict__ fhi, unsigned short* __restrict__ flo)
{
    int i = blockIdx.x*256 + threadIdx.x;
    int co = i & 511;
    float sacc = Bias[co];
    #pragma unroll
    for (int sk = 0; sk < 8; ++sk) sacc += skbuf[sk*524288 + i];
    float v = fmaxf(sacc, 0.f);
    unsigned short h = f2bf(v);
    fhi[i] = h;
    flo[i] = f2bf(v - bf2f(h));
}

// ===================== dec1: 4-way ci-split partial + reduce ===============
__global__ __launch_bounds__(128, 2)
void dec1_partial(const unsigned short* __restrict__ in,
                  const unsigned short* __restrict__ WT,
                  const int* __restrict__ cls_i,
                  float* __restrict__ dbuf)
{
    constexpr int CI = 512, CO = 256, HI = 4;
    constexpr int R = 6, C = 6, CK = 64, CKQ = 2, PITCH = 72;
    constexpr int NST = 9*CKQ;

    __shared__ __align__(16) unsigned short ilds[R*C*PITCH];

    const int sk  = blockIdx.x;
    const int co0 = blockIdx.y * 128;
    const int n   = blockIdx.z;
    const int e   = cls_i[n];
    const int t = threadIdx.x;
    const int w = t >> 6, lane = t & 63;
    const int s = lane & 15, q = lane >> 4;

    const unsigned short* Wbase = WT + (long)e*CO*9*CI;
    const unsigned short* inN   = in + (long)n*HI*HI*CI;

    int dyy[4], dxx[4];
    #pragma unroll
    for (int si = 0; si < 4; ++si) { dyy[si] = si*2 + (s>>3); dxx[si] = s & 7; }

    long wrow[4];
    #pragma unroll
    for (int tn = 0; tn < 4; ++tn)
        wrow[tn] = (long)(co0 + w*64 + tn*16 + s)*9*CI + q*8;

    f32x4 acc[4][4];
    #pragma unroll
    for (int si = 0; si < 4; ++si)
        #pragma unroll
        for (int tn = 0; tn < 4; ++tn)
            acc[si][tn] = (f32x4){0.f,0.f,0.f,0.f};

    for (int cc = 0; cc < CI/4; cc += CK) {
        const int ci0 = sk*(CI/4) + cc;
        for (int i8 = t; i8 < R*C*8; i8 += 128) {
            int pix = i8 >> 3, cs = i8 & 7;
            int r = pix / C, c = pix % C;
            int ih = r - 1, iw = c - 1;
            uint4 v = {0u,0u,0u,0u};
            if (ih >= 0 && ih < HI && iw >= 0 && iw < HI)
                v = *reinterpret_cast<const uint4*>(&inN[((long)ih*HI + iw)*CI + ci0 + cs*8]);
            *reinterpret_cast<uint4*>(&ilds[pix*PITCH + cs*8]) = v;
        }
        __syncthreads();

        bf16x8 a[3][4];
        #pragma unroll
        for (int pf = 0; pf < 3; ++pf) {
            const int kp = pf/CKQ, cp = pf%CKQ;
            #pragma unroll
            for (int tn = 0; tn < 4; ++tn)
                a[pf][tn] = *reinterpret_cast<const bf16x8*>(&Wbase[wrow[tn] + kp*CI + ci0 + cp*32]);
        }
        #pragma unroll
        for (int st = 0; st < NST; ++st) {
            const int slot = st % 3;
            bf16x8 acur[4];
            #pragma unroll
            for (int tn = 0; tn < 4; ++tn) acur[tn] = a[slot][tn];
            if (st + 3 < NST) {
                const int kp = (st+3)/CKQ, cp = (st+3)%CKQ;
                #pragma unroll
                for (int tn = 0; tn < 4; ++tn)
                    a[slot][tn] = *reinterpret_cast<const bf16x8*>(&Wbase[wrow[tn] + kp*CI + ci0 + cp*32]);
            }
            const int k = st/CKQ, ckq = st%CKQ;
            const int kh = k/3, kw = k%3;
            #pragma unroll
            for (int si = 0; si < 4; ++si) {
                const int ihr = ((dyy[si] + kh - 1) >> 1) + 1;
                const int iwr = ((dxx[si] + kw - 1) >> 1) + 1;
                bf16x8 b = *reinterpret_cast<const bf16x8*>(
                    &ilds[(ihr*C + iwr)*PITCH + ckq*32 + q*8]);
                #pragma unroll
                for (int tn = 0; tn < 4; ++tn)
                    acc[si][tn] = __builtin_amdgcn_mfma_f32_16x16x32_bf16(acur[tn], b, acc[si][tn], 0, 0, 0);
            }
        }
        __syncthreads();
    }

    #pragma unroll
    for (int si = 0; si < 4; ++si) {
        int px = dyy[si]*8 + dxx[si];
        #pragma unroll
        for (int tn = 0; tn < 4; ++tn) {
            int co_b = co0 + w*64 + tn*16 + q*4;
            long o = (((long)sk*64 + n)*64 + px)*256 + co_b;
            *reinterpret_cast<f32x4*>(&dbuf[o]) = acc[si][tn];
        }
    }
}

__global__ __launch_bounds__(256)
void dec1_reduce(const float* __restrict__ dbuf, const float* __restrict__ be1,
                 const int* __restrict__ cls_i, unsigned short* __restrict__ P)
{
    int i = blockIdx.x*256 + threadIdx.x;
    int n = i >> 14;
    int co = i & 255;
    int e = cls_i[n];
    float sacc = be1[e*256 + co];
    #pragma unroll
    for (int sk = 0; sk < 4; ++sk) sacc += dbuf[sk*1048576 + i];
    P[i] = f2bf(fmaxf(sacc, 0.f));
}

// ===================== fused weight transposes =============================
template<int CI>
__device__ __forceinline__ void trans_split_row(const float* __restrict__ src,
                                                unsigned short* __restrict__ hi,
                                                unsigned short* __restrict__ lo,
                                                int blk, float* buf, int t)
{
    const float* sp = src + (long)blk*(CI*9);
    for (int i = t; i < CI*9; i += 256) buf[i] = sp[i];
    __syncthreads();
    for (int i = t; i < CI*9; i += 256) {
        int k = i / CI, ci = i % CI;
        float v = buf[ci*9 + k];
        unsigned short h = f2bf(v);
        hi[(long)blk*(CI*9) + i] = h;
        lo[(long)blk*(CI*9) + i] = f2bf(v - bf2f(h));
    }
}

template<int CI>
__device__ __forceinline__ void trans_row(const float* __restrict__ src,
                                          unsigned short* __restrict__ dst,
                                          int blk, float* buf, int t)
{
    const float* sp = src + (long)blk*(CI*9);
    for (int i = t; i < CI*9; i += 256) buf[i] = sp[i];
    __syncthreads();
    for (int i = t; i < CI*9; i += 256) {
        int k = i / CI, ci = i % CI;
        dst[(long)blk*(CI*9) + i] = f2bf(buf[ci*9 + k]);
    }
}

__global__ __launch_bounds__(256)
void early_trans_kernel(const float* __restrict__ Wb2, const float* __restrict__ Wb3,
                        unsigned short* __restrict__ WB2hi, unsigned short* __restrict__ WB2lo,
                        unsigned short* __restrict__ WB3hi, unsigned short* __restrict__ WB3lo)
{
    __shared__ float buf[128*9];
    int b = blockIdx.x, t = threadIdx.x;
    if (b < 128) trans_split_row<64>(Wb2, WB2hi, WB2lo, b, buf, t);
    else         trans_split_row<128>(Wb3, WB3hi, WB3lo, b-128, buf, t);
}

__global__ __launch_bounds__(256)
void late_trans_kernel(const float* __restrict__ Wb4, const float* __restrict__ Wb5,
                       const float* __restrict__ We1, const float* __restrict__ We2,
                       const float* __restrict__ We3, const float* __restrict__ We4,
                       const float* __restrict__ We5,
                       unsigned short* __restrict__ WB4hi, unsigned short* __restrict__ WB4lo,
                       unsigned short* __restrict__ WB5hi, unsigned short* __restrict__ WB5lo,
                       unsigned short* __restrict__ WT1, unsigned short* __restrict__ WT2,
                       unsigned short* __restrict__ WT3, unsigned short* __restrict__ WT4,
                       unsigned short* __restrict__ WT5)
{
    __shared__ float buf[512*9];
    int b = blockIdx.x, t = threadIdx.x;
    if      (b < 512)  trans_split_row<256>(Wb4, WB4hi, WB4lo, b,      buf, t);
    else if (b < 1024) trans_split_row<512>(Wb5, WB5hi, WB5lo, b-512,  buf, t);
    else if (b < 2304) trans_row<512>(We1, WT1, b-1024, buf, t);
    else if (b < 2944) trans_row<256>(We2, WT2, b-2304, buf, t);
    else if (b < 3264) trans_row<128>(We3, WT3, b-2944, buf, t);
    else if (b < 3424) trans_row<64> (We4, WT4, b-3264, buf, t);
    else               trans_row<32> (We5, WT5, b-3424, buf, t);
}

// ===================== fused classifier ====================================
__global__ __launch_bounds__(128)
void classifier_kernel(const unsigned short* __restrict__ fh,
                       const unsigned short* __restrict__ fl,
                       const float* __restrict__ Wc1, const float* __restrict__ bc1,
                       const float* __restrict__ Wc2, const float* __restrict__ bc2,
                       float* __restrict__ out, int* __restrict__ cls_i)
{
    __shared__ float pooled[512];
    __shared__ float hidden[128];
    __shared__ float lg[5];
    const int n = blockIdx.x, t = threadIdx.x;

    for (int ci = t; ci < 512; ci += 128) {
        const unsigned short* ph = fh + (long)n*8192 + ci;
        const unsigned short* pl = fl + (long)n*8192 + ci;
        float sacc = 0.f;
        #pragma unroll
        for (int px = 0; px < 16; ++px)
            sacc += bf2f(ph[px*512]) + bf2f(pl[px*512]);
        pooled[ci] = sacc * (1.f/16.f);
    }
    __syncthreads();
    {
        const float* w = Wc1 + t*512;
        float sacc = 0.f;
        for (int k = 0; k < 512; ++k) sacc += pooled[k]*w[k];
        hidden[t] = fmaxf(sacc + bc1[t], 0.f);
    }
    __syncthreads();
    if (t < 5) {
        const float* w = Wc2 + t*128;
        float sacc = 0.f;
        for (int k = 0; k < 128; ++k) sacc += hidden[k]*w[k];
        sacc += bc2[t];
        out[n*5 + t] = sacc;
        lg[t] = sacc;
    }
    __syncthreads();
    if (t == 0) {
        int am = 0; float best = lg[0];
        #pragma unroll
        for (int k = 1; k < 5; ++k) if (lg[k] > best) { best = lg[k]; am = k; }
        out[320 + n] = (float)am;
        cls_i[n] = am;
    }
}

// ===================== bf16 MFMA decoder conv v2 (dec2/3) ==================
template<int CI,int CO,int HO,int NW>
__global__ __launch_bounds__(NW*64, 2)
void dec_conv_v2(const unsigned short* __restrict__ in,
                 const unsigned short* __restrict__ WT,
                 const float* __restrict__ Be,
                 const int* __restrict__ cls_i,
                 unsigned short* __restrict__ out)
{
    constexpr int HI = HO/2;
    constexpr int R = 6, C = 6;
    constexpr int CK = 64, CKQ = CK/32;
    constexpr int PITCH = CK + 8;
    constexpr int NTHR = NW*64;
    constexpr int NST = 9*CKQ;

    __shared__ __align__(16) unsigned short ilds[R*C*PITCH];

    const int n = blockIdx.z;
    const int e = cls_i[n];
    const int co0 = blockIdx.y * (NW*64);
    constexpr int TILES_X = HO/8;
    const int ty = blockIdx.x / TILES_X, tx = blockIdx.x % TILES_X;
    const int oh0 = ty*8, ow0 = tx*8;
    const int ih0 = oh0/2 - 1, iw0 = ow0/2 - 1;

    const int t = threadIdx.x;
    const int w = t >> 6, lane = t & 63;
    const int s = lane & 15, q = lane >> 4;

    const unsigned short* Wbase = WT + (long)e*CO*9*CI;
    const unsigned short* inN   = in + (long)n*HI*HI*CI;

    int dyy[4], dxx[4];
    #pragma unroll
    for (int si = 0; si < 4; ++si) { dyy[si] = si*2 + (s>>3); dxx[si] = s & 7; }

    long wrow[4];
    #pragma unroll
    for (int tn = 0; tn < 4; ++tn)
        wrow[tn] = (long)(co0 + w*64 + tn*16 + s)*9*CI + q*8;

    f32x4 acc[4][4];
    #pragma unroll
    for (int si = 0; si < 4; ++si)
        #pragma unroll
        for (int tn = 0; tn < 4; ++tn)
            acc[si][tn] = (f32x4){0.f,0.f,0.f,0.f};

    for (int ci0 = 0; ci0 < CI; ci0 += CK) {
        for (int i8 = t; i8 < R*C*8; i8 += NTHR) {
            int pix = i8 >> 3, cs = i8 & 7;
            int r = pix / C, c = pix % C;
            int ih = ih0 + r, iw = iw0 + c;
            uint4 v = {0u,0u,0u,0u};
            if (ih >= 0 && ih < HI && iw >= 0 && iw < HI)
                v = *reinterpret_cast<const uint4*>(&inN[((long)ih*HI + iw)*CI + ci0 + cs*8]);
            *reinterpret_cast<uint4*>(&ilds[pix*PITCH + cs*8]) = v;
        }
        __syncthreads();

        bf16x8 a[3][4];
        #pragma unroll
        for (int pf = 0; pf < 3; ++pf) {
            const int kp = pf/CKQ, cp = pf%CKQ;
            #pragma unroll
            for (int tn = 0; tn < 4; ++tn)
                a[pf][tn] = *reinterpret_cast<const bf16x8*>(&Wbase[wrow[tn] + kp*CI + ci0 + cp*32]);
        }
        #pragma unroll
        for (int st = 0; st < NST; ++st) {
            const int slot = st % 3;
            bf16x8 acur[4];
            #pragma unroll
            for (int tn = 0; tn < 4; ++tn) acur[tn] = a[slot][tn];
            if (st + 3 < NST) {
                const int kp = (st+3)/CKQ, cp = (st+3)%CKQ;
                #pragma unroll
                for (int tn = 0; tn < 4; ++tn)
                    a[slot][tn] = *reinterpret_cast<const bf16x8*>(&Wbase[wrow[tn] + kp*CI + ci0 + cp*32]);
            }
            const int k = st/CKQ, ckq = st%CKQ;
            const int kh = k/3, kw = k%3;
            #pragma unroll
            for (int si = 0; si < 4; ++si) {
                const int ihr = ((dyy[si] + kh - 1) >> 1) + 1;
                const int iwr = ((dxx[si] + kw - 1) >> 1) + 1;
                bf16x8 b = *reinterpret_cast<const bf16x8*>(
                    &ilds[(ihr*C + iwr)*PITCH + ckq*32 + q*8]);
                #pragma unroll
                for (int tn = 0; tn < 4; ++tn)
                    acc[si][tn] = __builtin_amdgcn_mfma_f32_16x16x32_bf16(acur[tn], b, acc[si][tn], 0, 0, 0);
            }
        }
        __syncthreads();
    }

    #pragma unroll
    for (int si = 0; si < 4; ++si) {
        int oh = oh0 + dyy[si], ow = ow0 + dxx[si];
        #pragma unroll
        for (int tn = 0; tn < 4; ++tn) {
            int co_b = co0 + w*64 + tn*16 + q*4;
            ushort4 st4;
            #pragma unroll
            for (int r = 0; r < 4; ++r) {
                float v = acc[si][tn][r] + Be[e*CO + co_b + r];
                v = fmaxf(v, 0.f);
                ((unsigned short*)&st4)[r] = f2bf(v);
            }
            *reinterpret_cast<ushort4*>(&out[(((long)n*HO + oh)*HO + ow)*CO + co_b]) = st4;
        }
    }
}

// ===================== bf16 MFMA decoder conv (dec4/5) =====================
template<int CI,int CO,int HO,int TH,int TW,int CO_T,int CK>
__global__ __launch_bounds__(256, 2)
void dec_conv_kernel(const unsigned short* __restrict__ in,
                     const unsigned short* __restrict__ WT,
                     const float* __restrict__ Be,
                     const int* __restrict__ cls_i,
                     unsigned short* __restrict__ out)
{
    constexpr int HI = HO/2;
    constexpr int R = TH/2 + 2, C = TW/2 + 2;
    constexpr int PITCH = CK + 8;
    constexpr int NT = CO_T/16;
    constexpr int S  = (TH*TW)/64;
    constexpr int SXT = TW/8;
    constexpr int CKQ = CK/32;
    constexpr int NST = 9*CKQ;

    __shared__ __align__(16) unsigned short ilds[R*C*PITCH];

    const int n = blockIdx.z;
    const int e = cls_i[n];
    const int co0 = blockIdx.y * CO_T;
    constexpr int TILES_X = HO/TW;
    const int ty = blockIdx.x / TILES_X, tx = blockIdx.x % TILES_X;
    const int oh0 = ty*TH, ow0 = tx*TW;
    const int ih0 = oh0/2 - 1, iw0 = ow0/2 - 1;

    const int t = threadIdx.x;
    const int w = t >> 6;
    const int lane = t & 63;
    const int s = lane & 15;
    const int q = lane >> 4;

    const unsigned short* Wbase = WT + ((long)e*CO + co0)*9*CI;
    const unsigned short* inN   = in + (long)n*HI*HI*CI;

    long wrow[NT];
    #pragma unroll
    for (int tn = 0; tn < NT; ++tn)
        wrow[tn] = (long)(tn*16 + s)*9*CI + q*8;

    f32x4 acc[S][NT];
    #pragma unroll
    for (int si = 0; si < S; ++si)
        #pragma unroll
        for (int tn = 0; tn < NT; ++tn)
            acc[si][tn] = (f32x4){0.f,0.f,0.f,0.f};

    int dy[S], dx[S];
    #pragma unroll
    for (int si = 0; si < S; ++si) {
        int sub = w + si*4;
        int sy = sub / SXT, sx = sub % SXT;
        dy[si] = sy*2 + (s >> 3);
        dx[si] = sx*8 + (s & 7);
    }

    for (int ci0 = 0; ci0 < CI; ci0 += CK) {
        constexpr int C8 = CK/8;
        for (int i8 = t; i8 < R*C*C8; i8 += 256) {
            int pix = i8 / C8, cs = i8 % C8;
            int r = pix / C, c = pix % C;
            int ih = ih0 + r, iw = iw0 + c;
            uint4 v = {0u,0u,0u,0u};
            if (ih >= 0 && ih < HI && iw >= 0 && iw < HI)
                v = *reinterpret_cast<const uint4*>(&inN[((long)ih*HI + iw)*CI + ci0 + cs*8]);
            *reinterpret_cast<uint4*>(&ilds[pix*PITCH + cs*8]) = v;
        }
        __syncthreads();

        bf16x8 a[3][NT];
        #pragma unroll
        for (int pf = 0; pf < 3 && pf < NST; ++pf) {
            const int kp = pf/CKQ, cp = pf%CKQ;
            #pragma unroll
            for (int tn = 0; tn < NT; ++tn)
                a[pf][tn] = *reinterpret_cast<const bf16x8*>(&Wbase[wrow[tn] + kp*CI + ci0 + cp*32]);
        }
        #pragma unroll
        for (int st = 0; st < NST; ++st) {
            const int slot = st % 3;
            bf16x8 acur[NT];
            #pragma unroll
            for (int tn = 0; tn < NT; ++tn) acur[tn] = a[slot][tn];
            if (st + 3 < NST) {
                const int kp = (st+3)/CKQ, cp = (st+3)%CKQ;
                #pragma unroll
                for (int tn = 0; tn < NT; ++tn)
                    a[slot][tn] = *reinterpret_cast<const bf16x8*>(&Wbase[wrow[tn] + kp*CI + ci0 + cp*32]);
            }
            const int k = st/CKQ, ckq = st%CKQ;
            const int kh = k/3, kw = k%3;
            #pragma unroll
            for (int si = 0; si < S; ++si) {
                int ihr = ((dy[si] + kh - 1) >> 1) + 1;
                int iwr = ((dx[si] + kw - 1) >> 1) + 1;
                bf16x8 b = *reinterpret_cast<const bf16x8*>(
                    &ilds[(ihr*C + iwr)*PITCH + ckq*32 + q*8]);
                #pragma unroll
                for (int tn = 0; tn < NT; ++tn)
                    acc[si][tn] = __builtin_amdgcn_mfma_f32_16x16x32_bf16(acur[tn], b, acc[si][tn], 0, 0, 0);
            }
        }
        __syncthreads();
    }

    #pragma unroll
    for (int si = 0; si < S; ++si) {
        int oh = oh0 + dy[si], ow = ow0 + dx[si];
        #pragma unroll
        for (int tn = 0; tn < NT; ++tn) {
            int co_b = co0 + tn*16 + q*4;
            ushort4 st4;
            #pragma unroll
            for (int r = 0; r < 4; ++r) {
                float v = acc[si][tn][r] + Be[e*CO + co_b + r];
                v = fmaxf(v, 0.f);
                ((unsigned short*)&st4)[r] = f2bf(v);
            }
            *reinterpret_cast<ushort4*>(&out[(((long)n*HO + oh)*HO + ow)*CO + co_b]) = st4;
        }
    }
}

// ===================== 1x1 head: NHWC bf16 -> NCHW fp32 ====================
__global__ __launch_bounds__(256) void head_kernel(const unsigned short* __restrict__ d5,
                                                   const float* __restrict__ Wh,
                                                   const float* __restrict__ bh,
                                                   const int* __restrict__ cls_i,
                                                   float* __restrict__ seg)
{
    int n = blockIdx.y;
    int p = blockIdx.x*256 + threadIdx.x;
    __shared__ float w[85];
    int e = cls_i[n];
    if (threadIdx.x < 80) w[threadIdx.x] = Wh[(long)e*80 + threadIdx.x];
    if (threadIdx.x < 5)  w[80+threadIdx.x] = bh[e*5 + threadIdx.x];
    __syncthreads();
    const unsigned short* dp = d5 + ((long)n*16384 + p)*16;
    uint4 u0 = *reinterpret_cast<const uint4*>(dp);
    uint4 u1 = *reinterpret_cast<const uint4*>(dp + 8);
    float x[16];
    unsigned int uu[4] = {u0.x, u0.y, u0.z, u0.w};
    unsigned int vv[4] = {u1.x, u1.y, u1.z, u1.w};
    #pragma unroll
    for (int i = 0; i < 4; ++i) {
        x[2*i+0] = __uint_as_float(uu[i] << 16);
        x[2*i+1] = __uint_as_float(uu[i] & 0xffff0000u);
        x[8+2*i+0] = __uint_as_float(vv[i] << 16);
        x[8+2*i+1] = __uint_as_float(vv[i] & 0xffff0000u);
    }
    #pragma unroll
    for (int co = 0; co < 5; ++co) {
        float sacc = w[80+co];
        #pragma unroll
        for (int ci = 0; ci < 16; ++ci) sacc += x[ci]*w[co*16+ci];
        seg[((long)n*5 + co)*16384 + p] = sacc;
    }
}

// ===========================================================================
extern "C" void kernel_launch(void* const* d_in, const int* in_sizes, int n_in,
                              void* d_out, int out_size, void* d_ws, size_t ws_size,
                              hipStream_t stream)
{
    const float* x   = (const float*)d_in[0];
    const float* Wb1 = (const float*)d_in[1];  const float* bb1 = (const float*)d_in[2];
    const float* Wb2 = (const float*)d_in[3];  const float* bb2 = (const float*)d_in[4];
    const float* Wb3 = (const float*)d_in[5];  const float* bb3 = (const float*)d_in[6];
    const float* Wb4 = (const float*)d_in[7];  const float* bb4 = (const float*)d_in[8];
    const float* Wb5 = (const float*)d_in[9];  const float* bb5 = (const float*)d_in[10];
    const float* Wc1 = (const float*)d_in[11]; const float* bc1 = (const float*)d_in[12];
    const float* Wc2 = (const float*)d_in[13]; const float* bc2 = (const float*)d_in[14];
    const float* We1 = (const float*)d_in[15]; const float* be1 = (const float*)d_in[16];
    const float* We2 = (const float*)d_in[17]; const float* be2 = (const float*)d_in[18];
    const float* We3 = (const float*)d_in[19]; const float* be3 = (const float*)d_in[20];
    const float* We4 = (const float*)d_in[21]; const float* be4 = (const float*)d_in[22];
    const float* We5 = (const float*)d_in[23]; const float* be5 = (const float*)d_in[24];
    const float* We6 = (const float*)d_in[25]; const float* be6 = (const float*)d_in[26];

    float* out = (float*)d_out;
    char* ws = (char*)d_ws;

    // ---- X region (67 MB): H1 -> {H3, WB4/5} -> SKBUF5 -> {P, Q/DBUF1, WT1-5}
    unsigned short* H1hi = (unsigned short*)(ws + 0);
    unsigned short* H1lo = (unsigned short*)(ws + 33554432);
    unsigned short* H3hi = (unsigned short*)(ws + 0);
    unsigned short* H3lo = (unsigned short*)(ws + 8388608);
    unsigned short* WB4hi = (unsigned short*)(ws + 16777216);
    unsigned short* WB4lo = (unsigned short*)(ws + 19136512);
    unsigned short* WB5hi = (unsigned short*)(ws + 21495808);
    unsigned short* WB5lo = (unsigned short*)(ws + 26214400);
    float*          SKBUF5 = (float*)(ws + 0);
    unsigned short* P    = (unsigned short*)(ws + 0);
    unsigned short* Q    = (unsigned short*)(ws + 33554432);
    float*          DBUF1 = (float*)(ws + 33554432);
    unsigned short* WT1  = (unsigned short*)(ws + 50331648);
    unsigned short* WT2  = (unsigned short*)(ws + 62128128);
    unsigned short* WT3  = (unsigned short*)(ws + 65077248);
    unsigned short* WT4  = (unsigned short*)(ws + 65814528);
    unsigned short* WT5  = (unsigned short*)(ws + 65998848);

    // ---- Y region (33.5 MB): H2 -> {H4, FEATS, pooled/hidden/cls} ----
    char* Y = ws + 67108864;
    unsigned short* H2hi = (unsigned short*)(Y + 0);
    unsigned short* H2lo = (unsigned short*)(Y + 16777216);
    unsigned short* H4hi = (unsigned short*)(Y + 0);
    unsigned short* H4lo = (unsigned short*)(Y + 4194304);
    unsigned short* FShi = (unsigned short*)(Y + 8388608);
    unsigned short* FSlo = (unsigned short*)(Y + 9437184);
    int*   cls_i  = (int*)(Y + 10649600);

    // ---- W23 tail (1.5 MB) ----
    char* W23 = ws + 100663296;
    unsigned short* WB2hi = (unsigned short*)(W23 + 0);
    unsigned short* WB2lo = (unsigned short*)(W23 + 147456);
    unsigned short* WB3hi = (unsigned short*)(W23 + 294912);
    unsigned short* WB3lo = (unsigned short*)(W23 + 884736);

    // ---- early transposes (WB2+WB3 fused) ----
    hipLaunchKernelGGL(early_trans_kernel, dim3(384), dim3(256), 0, stream,
                       Wb2, Wb3, WB2hi, WB2lo, WB3hi, WB3lo);

    // ---- conv1 (fp32 direct, split output) ----
    hipLaunchKernelGGL(conv1_kernel, dim3(64,2,64), dim3(256), 0, stream, x, Wb1, bb1, H1hi, H1lo);

    // ---- conv2 ----
    hipLaunchKernelGGL((bb_conv_v3<64,128,32,2>), dim3(16,1,64), dim3(128), 0, stream,
                       H1hi, H1lo, WB2hi, WB2lo, bb2, H2hi, H2lo);

    // ---- H1 dead: all remaining transposes in one launch ----
    hipLaunchKernelGGL(late_trans_kernel, dim3(3504), dim3(256), 0, stream,
                       Wb4, Wb5, We1, We2, We3, We4, We5,
                       WB4hi, WB4lo, WB5hi, WB5lo, WT1, WT2, WT3, WT4, WT5);

    // ---- conv3/conv4 ----
    hipLaunchKernelGGL((bb_conv_v3<128,256,16,2>), dim3(4,2,64), dim3(128), 0, stream,
                       H2hi, H2lo, WB3hi, WB3lo, bb3, H3hi, H3lo);
    hipLaunchKernelGGL((bb_conv_v3<256,512, 8,2>), dim3(1,4,64), dim3(128), 0, stream,
                       H3hi, H3lo, WB4hi, WB4lo, bb4, H4hi, H4lo);

    // ---- conv5: split-K partials + reduce ----
    hipLaunchKernelGGL(conv5_partial, dim3(8,4,16), dim3(128), 0, stream,
                       H4hi, H4lo, WB5hi, WB5lo, SKBUF5);
    hipLaunchKernelGGL(conv5_reduce, dim3(2048), dim3(256), 0, stream,
                       SKBUF5, bb5, FShi, FSlo);

    // ---- classifier (pool+fc1+fc2+argmax fused) ----
    hipLaunchKernelGGL(classifier_kernel, dim3(64), dim3(128), 0, stream,
                       FShi, FSlo, Wc1, bc1, Wc2, bc2, out, cls_i);

    // ---- dec1: split-K partials + reduce -> P ----
    hipLaunchKernelGGL(dec1_partial, dim3(4,2,64), dim3(128), 0, stream,
                       FShi, WT1, cls_i, DBUF1);
    hipLaunchKernelGGL(dec1_reduce, dim3(4096), dim3(256), 0, stream,
                       DBUF1, be1, cls_i, P);

    // ---- dec2..5: P -> Q -> P -> Q -> P ----
    hipLaunchKernelGGL((dec_conv_v2<256,128, 16,2>), dim3(4, 1,64), dim3(128), 0, stream, P, WT2, be2, cls_i, Q);
    hipLaunchKernelGGL((dec_conv_v2<128, 64, 32,1>), dim3(16,1,64), dim3(64),  0, stream, Q, WT3, be3, cls_i, P);
    hipLaunchKernelGGL((dec_conv_kernel< 64, 32, 64, 16,16, 32,64>), dim3(16, 1,64), dim3(256), 0, stream, P, WT4, be4, cls_i, Q);
    hipLaunchKernelGGL((dec_conv_kernel< 32, 16,128, 16,32, 16,32>), dim3(32, 1,64), dim3(256), 0, stream, Q, WT5, be5, cls_i, P);

    // ---- 1x1 head -> seg (NCHW fp32) ----
    hipLaunchKernelGGL(head_kernel, dim3(64,64), dim3(256), 0, stream, P, We6, be6, cls_i, out + 384);
}

// Round 8
// 649.195 us; speedup vs baseline: 1.1522x; 1.1522x over previous
//
#include <hip/hip_runtime.h>
#include <hip/hip_bf16.h>

// ---------------------------------------------------------------------------
// R8: revert conv2-4 + conv5_partial to proven R6 structure (R7 pass-split
// regressed +27%: doubled barriers + 1.5x weight reads). Keep R7 launch
// fusions. New: fuse dec5 + 1x1 head (saves 67 MB traffic + 1 launch).
// ---------------------------------------------------------------------------

typedef __attribute__((ext_vector_type(8))) short bf16x8;   // 8 bf16 = 4 VGPRs
typedef __attribute__((ext_vector_type(4))) float f32x4;

static __device__ __forceinline__ unsigned short f2bf(float f) {
    __hip_bfloat16 h = __float2bfloat16(f);
    return *reinterpret_cast<unsigned short*>(&h);
}
static __device__ __forceinline__ float bf2f(unsigned short u) {
    return __uint_as_float(((unsigned int)u) << 16);
}

// ===================== conv1: fp32 direct, split NHWC output ===============
__global__ __launch_bounds__(256)
void conv1_kernel(const float* __restrict__ in, const float* __restrict__ W,
                  const float* __restrict__ Bias,
                  unsigned short* __restrict__ out_hi,
                  unsigned short* __restrict__ out_lo)
{
    constexpr int R = 17, C = 17;
    __shared__ float ilds[3*R*C];
    __shared__ float wlds[27*32];
    const int n = blockIdx.z, co0 = blockIdx.y*32;
    const int ty = blockIdx.x >> 3, tx = blockIdx.x & 7;
    const int oh0 = ty*8, ow0 = tx*8;
    const int t = threadIdx.x, p = t & 63, grp = t >> 6;
    const int py = p >> 3, px = p & 7;
    const int r0 = 2*oh0, c0 = 2*ow0;

    const float* ibase = in + (long)n*3*16384;
    for (int idx = t; idx < 3*R*C; idx += 256) {
        int ck = idx/(R*C), rc = idx%(R*C);
        int r = rc/C, c = rc%C;
        int ih = r0+r, iw = c0+c;
        float v = 0.f;
        if (ih < 128 && iw < 128) v = ibase[ck*16384 + ih*128 + iw];
        ilds[idx] = v;
    }
    for (int idx = t; idx < 32*27; idx += 256) {
        int co = idx & 31, rem = idx >> 5;
        wlds[rem*32 + co] = W[(co0+co)*27 + rem];
    }
    __syncthreads();

    float acc[8];
    #pragma unroll
    for (int i=0;i<8;i++) acc[i]=0.f;

    #pragma unroll
    for (int ck = 0; ck < 3; ++ck) {
        float xv[9];
        #pragma unroll
        for (int kh = 0; kh < 3; ++kh)
            #pragma unroll
            for (int kw = 0; kw < 3; ++kw)
                xv[kh*3+kw] = ilds[ck*289 + (2*py+kh)*17 + 2*px+kw];
        #pragma unroll
        for (int k = 0; k < 9; ++k) {
            #pragma unroll
            for (int g = 0; g < 2; ++g) {
                const float4 w = *reinterpret_cast<const float4*>(
                    &wlds[(ck*9+k)*32 + grp*8 + g*4]);
                acc[g*4+0] += xv[k]*w.x;
                acc[g*4+1] += xv[k]*w.y;
                acc[g*4+2] += xv[k]*w.z;
                acc[g*4+3] += xv[k]*w.w;
            }
        }
    }

    const long obase = (((long)n*64 + oh0+py)*64 + ow0+px)*64 + co0 + grp*8;
    #pragma unroll
    for (int g = 0; g < 2; ++g) {
        ushort4 sh, sl;
        #pragma unroll
        for (int j = 0; j < 4; ++j) {
            int co = co0 + grp*8 + g*4 + j;
            float v = fmaxf(acc[g*4+j] + Bias[co], 0.f);
            unsigned short h = f2bf(v);
            ((unsigned short*)&sh)[j] = h;
            ((unsigned short*)&sl)[j] = f2bf(v - bf2f(h));
        }
        *reinterpret_cast<ushort4*>(&out_hi[obase + g*4]) = sh;
        *reinterpret_cast<ushort4*>(&out_lo[obase + g*4]) = sl;
    }
}

// ===================== split-bf16 MFMA stride-2 conv (R6 exact) ============
// Wave tile: 64co x 64px (NT=4, S=4). NW co-waves per block.
template<int CI,int CO,int HO,int NW,int NPACK>
__global__ __launch_bounds__(NW*64, 2)
void bb_conv_v2(const unsigned short* __restrict__ in_hi,
                const unsigned short* __restrict__ in_lo,
                const unsigned short* __restrict__ Whi,
                const unsigned short* __restrict__ Wlo,
                const float* __restrict__ Bias,
                unsigned short* __restrict__ out_hi,
                unsigned short* __restrict__ out_lo)
{
    constexpr int HI = HO*2;
    constexpr int TH = (NPACK==1) ? 8 : 4;
    constexpr int TW = TH;
    constexpr int R  = 2*TH+1, C = 2*TW+1;
    constexpr int CK = 32;
    constexpr int PITCH = CK + 8;
    constexpr int CO_T  = NW*64;
    constexpr int NTHR  = NW*64;

    __shared__ __align__(16) unsigned short hi_lds[NPACK*R*C*PITCH];
    __shared__ __align__(16) unsigned short lo_lds[NPACK*R*C*PITCH];

    const int n0  = blockIdx.z * NPACK;
    const int co0 = blockIdx.y * CO_T;
    constexpr int TILES_X = (NPACK==1) ? (HO/TW) : 1;
    const int ty = blockIdx.x / TILES_X, tx = blockIdx.x % TILES_X;
    const int oh0 = ty*TH, ow0 = tx*TW;
    const int r0 = 2*oh0, c0 = 2*ow0;

    const int t = threadIdx.x;
    const int w = t >> 6, lane = t & 63;
    const int s = lane & 15, q = lane >> 4;

    int dyy[4], dxx[4], tb[4];
    #pragma unroll
    for (int si = 0; si < 4; ++si) {
        if (NPACK == 1) { dyy[si] = si*2 + (s>>3); dxx[si] = s & 7; tb[si] = 0; }
        else            { dyy[si] = s >> 2;        dxx[si] = s & 3; tb[si] = si*R*C*PITCH; }
    }

    int wrow[4];
    #pragma unroll
    for (int tn = 0; tn < 4; ++tn)
        wrow[tn] = (co0 + w*64 + tn*16 + s)*9*CI + q*8;

    f32x4 acc[4][4];
    #pragma unroll
    for (int si = 0; si < 4; ++si)
        #pragma unroll
        for (int tn = 0; tn < 4; ++tn)
            acc[si][tn] = (f32x4){0.f,0.f,0.f,0.f};

    for (int ci0 = 0; ci0 < CI; ci0 += CK) {
        constexpr int C8  = CK/8;
        constexpr int PXW = R*C*C8;
        for (int i8 = t; i8 < NPACK*PXW; i8 += NTHR) {
            int ti = i8 / PXW, rem = i8 % PXW;
            int pix = rem / C8, cs = rem % C8;
            int r = pix / C, c = pix % C;
            int ih = r0 + r, iw = c0 + c;
            uint4 vh = {0u,0u,0u,0u}, vl = {0u,0u,0u,0u};
            if (ih < HI && iw < HI) {
                long off = (((long)(n0+ti)*HI + ih)*HI + iw)*CI + ci0 + cs*8;
                vh = *reinterpret_cast<const uint4*>(&in_hi[off]);
                vl = *reinterpret_cast<const uint4*>(&in_lo[off]);
            }
            *reinterpret_cast<uint4*>(&hi_lds[(ti*R*C + pix)*PITCH + cs*8]) = vh;
            *reinterpret_cast<uint4*>(&lo_lds[(ti*R*C + pix)*PITCH + cs*8]) = vl;
        }
        __syncthreads();

        bf16x8 ah[2][4], al[2][4];
        #pragma unroll
        for (int tn = 0; tn < 4; ++tn) {
            const int wo = wrow[tn] + ci0;
            ah[0][tn] = *reinterpret_cast<const bf16x8*>(&Whi[wo]);
            al[0][tn] = *reinterpret_cast<const bf16x8*>(&Wlo[wo]);
        }
        #pragma unroll
        for (int k = 0; k < 9; ++k) {
            const int cur = k & 1, nxt = cur ^ 1;
            if (k < 8) {
                #pragma unroll
                for (int tn = 0; tn < 4; ++tn) {
                    const int wo = wrow[tn] + (k+1)*CI + ci0;
                    ah[nxt][tn] = *reinterpret_cast<const bf16x8*>(&Whi[wo]);
                    al[nxt][tn] = *reinterpret_cast<const bf16x8*>(&Wlo[wo]);
                }
            }
            const int kh = k/3, kw = k%3;
            bf16x8 bh[4], bl[4];
            #pragma unroll
            for (int si = 0; si < 4; ++si) {
                const int pi = tb[si] + ((2*dyy[si]+kh)*C + 2*dxx[si]+kw)*PITCH + q*8;
                bh[si] = *reinterpret_cast<const bf16x8*>(&hi_lds[pi]);
                bl[si] = *reinterpret_cast<const bf16x8*>(&lo_lds[pi]);
            }
            #pragma unroll
            for (int si = 0; si < 4; ++si)
                #pragma unroll
                for (int tn = 0; tn < 4; ++tn) {
                    acc[si][tn] = __builtin_amdgcn_mfma_f32_16x16x32_bf16(ah[cur][tn], bh[si], acc[si][tn], 0,0,0);
                    acc[si][tn] = __builtin_amdgcn_mfma_f32_16x16x32_bf16(ah[cur][tn], bl[si], acc[si][tn], 0,0,0);
                    acc[si][tn] = __builtin_amdgcn_mfma_f32_16x16x32_bf16(al[cur][tn], bh[si], acc[si][tn], 0,0,0);
                }
        }
        __syncthreads();
    }

    #pragma unroll
    for (int si = 0; si < 4; ++si) {
        const int n_s = (NPACK==1) ? n0 : (n0 + si);
        const int oh  = (NPACK==1) ? (oh0 + dyy[si]) : dyy[si];
        const int ow  = (NPACK==1) ? (ow0 + dxx[si]) : dxx[si];
        #pragma unroll
        for (int tn = 0; tn < 4; ++tn) {
            int co_b = co0 + w*64 + tn*16 + q*4;
            ushort4 sh, sl;
            #pragma unroll
            for (int r = 0; r < 4; ++r) {
                float v = fmaxf(acc[si][tn][r] + Bias[co_b + r], 0.f);
                unsigned short h = f2bf(v);
                ((unsigned short*)&sh)[r] = h;
                ((unsigned short*)&sl)[r] = f2bf(v - bf2f(h));
            }
            long ob = (((long)n_s*HO + oh)*HO + ow)*CO + co_b;
            *reinterpret_cast<ushort4*>(&out_hi[ob]) = sh;
            *reinterpret_cast<ushort4*>(&out_lo[ob]) = sl;
        }
    }
}

// ===================== conv5: 8-way ci-split partial + reduce (R6) =========
__global__ __launch_bounds__(128, 2)
void conv5_partial(const unsigned short* __restrict__ in_hi,
                   const unsigned short* __restrict__ in_lo,
                   const unsigned short* __restrict__ Whi,
                   const unsigned short* __restrict__ Wlo,
                   float* __restrict__ skbuf)
{
    constexpr int CI = 512, HI = 8;
    constexpr int R = 9, C = 9, CK = 32, PITCH = 40;

    __shared__ __align__(16) unsigned short hi_lds[4*R*C*PITCH];
    __shared__ __align__(16) unsigned short lo_lds[4*R*C*PITCH];

    const int sk  = blockIdx.x;
    const int co0 = blockIdx.y * 128;
    const int n0  = blockIdx.z * 4;
    const int t = threadIdx.x;
    const int w = t >> 6, lane = t & 63;
    const int s = lane & 15, q = lane >> 4;
    const int dyy = s >> 2, dxx = s & 3;

    int wrow[4];
    #pragma unroll
    for (int tn = 0; tn < 4; ++tn)
        wrow[tn] = (co0 + w*64 + tn*16 + s)*9*CI + q*8;

    f32x4 acc[4][4];
    #pragma unroll
    for (int si = 0; si < 4; ++si)
        #pragma unroll
        for (int tn = 0; tn < 4; ++tn)
            acc[si][tn] = (f32x4){0.f,0.f,0.f,0.f};

    for (int cc = 0; cc < 64; cc += CK) {
        const int ci0 = sk*64 + cc;
        for (int i8 = t; i8 < 4*324; i8 += 128) {
            int ti = i8 / 324, rem = i8 % 324;
            int pix = rem >> 2, cs = rem & 3;
            int r = pix / C, c = pix % C;
            uint4 vh = {0u,0u,0u,0u}, vl = {0u,0u,0u,0u};
            if (r < HI && c < HI) {
                long off = (((long)(n0+ti)*HI + r)*HI + c)*CI + ci0 + cs*8;
                vh = *reinterpret_cast<const uint4*>(&in_hi[off]);
                vl = *reinterpret_cast<const uint4*>(&in_lo[off]);
            }
            *reinterpret_cast<uint4*>(&hi_lds[(ti*R*C + pix)*PITCH + cs*8]) = vh;
            *reinterpret_cast<uint4*>(&lo_lds[(ti*R*C + pix)*PITCH + cs*8]) = vl;
        }
        __syncthreads();

        bf16x8 ah[2][4], al[2][4];
        #pragma unroll
        for (int tn = 0; tn < 4; ++tn) {
            const int wo = wrow[tn] + ci0;
            ah[0][tn] = *reinterpret_cast<const bf16x8*>(&Whi[wo]);
            al[0][tn] = *reinterpret_cast<const bf16x8*>(&Wlo[wo]);
        }
        #pragma unroll
        for (int k = 0; k < 9; ++k) {
            const int cur = k & 1, nxt = cur ^ 1;
            if (k < 8) {
                #pragma unroll
                for (int tn = 0; tn < 4; ++tn) {
                    const int wo = wrow[tn] + (k+1)*CI + ci0;
                    ah[nxt][tn] = *reinterpret_cast<const bf16x8*>(&Whi[wo]);
                    al[nxt][tn] = *reinterpret_cast<const bf16x8*>(&Wlo[wo]);
                }
            }
            const int kh = k/3, kw = k%3;
            bf16x8 bh[4], bl[4];
            #pragma unroll
            for (int si = 0; si < 4; ++si) {
                const int pi = si*R*C*PITCH + ((2*dyy+kh)*C + 2*dxx+kw)*PITCH + q*8;
                bh[si] = *reinterpret_cast<const bf16x8*>(&hi_lds[pi]);
                bl[si] = *reinterpret_cast<const bf16x8*>(&lo_lds[pi]);
            }
            #pragma unroll
            for (int si = 0; si < 4; ++si)
                #pragma unroll
                for (int tn = 0; tn < 4; ++tn) {
                    acc[si][tn] = __builtin_amdgcn_mfma_f32_16x16x32_bf16(ah[cur][tn], bh[si], acc[si][tn], 0,0,0);
                    acc[si][tn] = __builtin_amdgcn_mfma_f32_16x16x32_bf16(ah[cur][tn], bl[si], acc[si][tn], 0,0,0);
                    acc[si][tn] = __builtin_amdgcn_mfma_f32_16x16x32_bf16(al[cur][tn], bh[si], acc[si][tn], 0,0,0);
                }
        }
        __syncthreads();
    }

    #pragma unroll
    for (int si = 0; si < 4; ++si) {
        #pragma unroll
        for (int tn = 0; tn < 4; ++tn) {
            int co_b = co0 + w*64 + tn*16 + q*4;
            long o = (((long)sk*64 + n0+si)*16 + s)*512 + co_b;
            *reinterpret_cast<f32x4*>(&skbuf[o]) = acc[si][tn];
        }
    }
}

__global__ __launch_bounds__(256)
void conv5_reduce(const float* __restrict__ skbuf, const float* __restrict__ Bias,
                  unsigned short* __restrict__ fhi, unsigned short* __restrict__ flo)
{
    int i = blockIdx.x*256 + threadIdx.x;
    int co = i & 511;
    float sacc = Bias[co];
    #pragma unroll
    for (int sk = 0; sk < 8; ++sk) sacc += skbuf[sk*524288 + i];
    float v = fmaxf(sacc, 0.f);
    unsigned short h = f2bf(v);
    fhi[i] = h;
    flo[i] = f2bf(v - bf2f(h));
}

// ===================== dec1: 4-way ci-split partial + reduce ===============
__global__ __launch_bounds__(128, 2)
void dec1_partial(const unsigned short* __restrict__ in,
                  const unsigned short* __restrict__ WT,
                  const int* __restrict__ cls_i,
                  float* __restrict__ dbuf)
{
    constexpr int CI = 512, CO = 256, HI = 4;
    constexpr int R = 6, C = 6, CK = 64, CKQ = 2, PITCH = 72;
    constexpr int NST = 9*CKQ;

    __shared__ __align__(16) unsigned short ilds[R*C*PITCH];

    const int sk  = blockIdx.x;
    const int co0 = blockIdx.y * 128;
    const int n   = blockIdx.z;
    const int e   = cls_i[n];
    const int t = threadIdx.x;
    const int w = t >> 6, lane = t & 63;
    const int s = lane & 15, q = lane >> 4;

    const unsigned short* Wbase = WT + (long)e*CO*9*CI;
    const unsigned short* inN   = in + (long)n*HI*HI*CI;

    int dyy[4], dxx[4];
    #pragma unroll
    for (int si = 0; si < 4; ++si) { dyy[si] = si*2 + (s>>3); dxx[si] = s & 7; }

    long wrow[4];
    #pragma unroll
    for (int tn = 0; tn < 4; ++tn)
        wrow[tn] = (long)(co0 + w*64 + tn*16 + s)*9*CI + q*8;

    f32x4 acc[4][4];
    #pragma unroll
    for (int si = 0; si < 4; ++si)
        #pragma unroll
        for (int tn = 0; tn < 4; ++tn)
            acc[si][tn] = (f32x4){0.f,0.f,0.f,0.f};

    for (int cc = 0; cc < CI/4; cc += CK) {
        const int ci0 = sk*(CI/4) + cc;
        for (int i8 = t; i8 < R*C*8; i8 += 128) {
            int pix = i8 >> 3, cs = i8 & 7;
            int r = pix / C, c = pix % C;
            int ih = r - 1, iw = c - 1;
            uint4 v = {0u,0u,0u,0u};
            if (ih >= 0 && ih < HI && iw >= 0 && iw < HI)
                v = *reinterpret_cast<const uint4*>(&inN[((long)ih*HI + iw)*CI + ci0 + cs*8]);
            *reinterpret_cast<uint4*>(&ilds[pix*PITCH + cs*8]) = v;
        }
        __syncthreads();

        bf16x8 a[3][4];
        #pragma unroll
        for (int pf = 0; pf < 3; ++pf) {
            const int kp = pf/CKQ, cp = pf%CKQ;
            #pragma unroll
            for (int tn = 0; tn < 4; ++tn)
                a[pf][tn] = *reinterpret_cast<const bf16x8*>(&Wbase[wrow[tn] + kp*CI + ci0 + cp*32]);
        }
        #pragma unroll
        for (int st = 0; st < NST; ++st) {
            const int slot = st % 3;
            bf16x8 acur[4];
            #pragma unroll
            for (int tn = 0; tn < 4; ++tn) acur[tn] = a[slot][tn];
            if (st + 3 < NST) {
                const int kp = (st+3)/CKQ, cp = (st+3)%CKQ;
                #pragma unroll
                for (int tn = 0; tn < 4; ++tn)
                    a[slot][tn] = *reinterpret_cast<const bf16x8*>(&Wbase[wrow[tn] + kp*CI + ci0 + cp*32]);
            }
            const int k = st/CKQ, ckq = st%CKQ;
            const int kh = k/3, kw = k%3;
            #pragma unroll
            for (int si = 0; si < 4; ++si) {
                const int ihr = ((dyy[si] + kh - 1) >> 1) + 1;
                const int iwr = ((dxx[si] + kw - 1) >> 1) + 1;
                bf16x8 b = *reinterpret_cast<const bf16x8*>(
                    &ilds[(ihr*C + iwr)*PITCH + ckq*32 + q*8]);
                #pragma unroll
                for (int tn = 0; tn < 4; ++tn)
                    acc[si][tn] = __builtin_amdgcn_mfma_f32_16x16x32_bf16(acur[tn], b, acc[si][tn], 0, 0, 0);
            }
        }
        __syncthreads();
    }

    #pragma unroll
    for (int si = 0; si < 4; ++si) {
        int px = dyy[si]*8 + dxx[si];
        #pragma unroll
        for (int tn = 0; tn < 4; ++tn) {
            int co_b = co0 + w*64 + tn*16 + q*4;
            long o = (((long)sk*64 + n)*64 + px)*256 + co_b;
            *reinterpret_cast<f32x4*>(&dbuf[o]) = acc[si][tn];
        }
    }
}

__global__ __launch_bounds__(256)
void dec1_reduce(const float* __restrict__ dbuf, const float* __restrict__ be1,
                 const int* __restrict__ cls_i, unsigned short* __restrict__ P)
{
    int i = blockIdx.x*256 + threadIdx.x;
    int n = i >> 14;
    int co = i & 255;
    int e = cls_i[n];
    float sacc = be1[e*256 + co];
    #pragma unroll
    for (int sk = 0; sk < 4; ++sk) sacc += dbuf[sk*1048576 + i];
    P[i] = f2bf(fmaxf(sacc, 0.f));
}

// ===================== fused weight transposes =============================
template<int CI>
__device__ __forceinline__ void trans_split_row(const float* __restrict__ src,
                                                unsigned short* __restrict__ hi,
                                                unsigned short* __restrict__ lo,
                                                int blk, float* buf, int t)
{
    const float* sp = src + (long)blk*(CI*9);
    for (int i = t; i < CI*9; i += 256) buf[i] = sp[i];
    __syncthreads();
    for (int i = t; i < CI*9; i += 256) {
        int k = i / CI, ci = i % CI;
        float v = buf[ci*9 + k];
        unsigned short h = f2bf(v);
        hi[(long)blk*(CI*9) + i] = h;
        lo[(long)blk*(CI*9) + i] = f2bf(v - bf2f(h));
    }
}

template<int CI>
__device__ __forceinline__ void trans_row(const float* __restrict__ src,
                                          unsigned short* __restrict__ dst,
                                          int blk, float* buf, int t)
{
    const float* sp = src + (long)blk*(CI*9);
    for (int i = t; i < CI*9; i += 256) buf[i] = sp[i];
    __syncthreads();
    for (int i = t; i < CI*9; i += 256) {
        int k = i / CI, ci = i % CI;
        dst[(long)blk*(CI*9) + i] = f2bf(buf[ci*9 + k]);
    }
}

__global__ __launch_bounds__(256)
void early_trans_kernel(const float* __restrict__ Wb2, const float* __restrict__ Wb3,
                        unsigned short* __restrict__ WB2hi, unsigned short* __restrict__ WB2lo,
                        unsigned short* __restrict__ WB3hi, unsigned short* __restrict__ WB3lo)
{
    __shared__ float buf[128*9];
    int b = blockIdx.x, t = threadIdx.x;
    if (b < 128) trans_split_row<64>(Wb2, WB2hi, WB2lo, b, buf, t);
    else         trans_split_row<128>(Wb3, WB3hi, WB3lo, b-128, buf, t);
}

__global__ __launch_bounds__(256)
void late_trans_kernel(const float* __restrict__ Wb4, const float* __restrict__ Wb5,
                       const float* __restrict__ We1, const float* __restrict__ We2,
                       const float* __restrict__ We3, const float* __restrict__ We4,
                       const float* __restrict__ We5,
                       unsigned short* __restrict__ WB4hi, unsigned short* __restrict__ WB4lo,
                       unsigned short* __restrict__ WB5hi, unsigned short* __restrict__ WB5lo,
                       unsigned short* __restrict__ WT1, unsigned short* __restrict__ WT2,
                       unsigned short* __restrict__ WT3, unsigned short* __restrict__ WT4,
                       unsigned short* __restrict__ WT5)
{
    __shared__ float buf[512*9];
    int b = blockIdx.x, t = threadIdx.x;
    if      (b < 512)  trans_split_row<256>(Wb4, WB4hi, WB4lo, b,      buf, t);
    else if (b < 1024) trans_split_row<512>(Wb5, WB5hi, WB5lo, b-512,  buf, t);
    else if (b < 2304) trans_row<512>(We1, WT1, b-1024, buf, t);
    else if (b < 2944) trans_row<256>(We2, WT2, b-2304, buf, t);
    else if (b < 3264) trans_row<128>(We3, WT3, b-2944, buf, t);
    else if (b < 3424) trans_row<64> (We4, WT4, b-3264, buf, t);
    else               trans_row<32> (We5, WT5, b-3424, buf, t);
}

// ===================== fused classifier ====================================
__global__ __launch_bounds__(128)
void classifier_kernel(const unsigned short* __restrict__ fh,
                       const unsigned short* __restrict__ fl,
                       const float* __restrict__ Wc1, const float* __restrict__ bc1,
                       const float* __restrict__ Wc2, const float* __restrict__ bc2,
                       float* __restrict__ out, int* __restrict__ cls_i)
{
    __shared__ float pooled[512];
    __shared__ float hidden[128];
    __shared__ float lg[5];
    const int n = blockIdx.x, t = threadIdx.x;

    for (int ci = t; ci < 512; ci += 128) {
        const unsigned short* ph = fh + (long)n*8192 + ci;
        const unsigned short* pl = fl + (long)n*8192 + ci;
        float sacc = 0.f;
        #pragma unroll
        for (int px = 0; px < 16; ++px)
            sacc += bf2f(ph[px*512]) + bf2f(pl[px*512]);
        pooled[ci] = sacc * (1.f/16.f);
    }
    __syncthreads();
    {
        const float* w = Wc1 + t*512;
        float sacc = 0.f;
        for (int k = 0; k < 512; ++k) sacc += pooled[k]*w[k];
        hidden[t] = fmaxf(sacc + bc1[t], 0.f);
    }
    __syncthreads();
    if (t < 5) {
        const float* w = Wc2 + t*128;
        float sacc = 0.f;
        for (int k = 0; k < 128; ++k) sacc += hidden[k]*w[k];
        sacc += bc2[t];
        out[n*5 + t] = sacc;
        lg[t] = sacc;
    }
    __syncthreads();
    if (t == 0) {
        int am = 0; float best = lg[0];
        #pragma unroll
        for (int k = 1; k < 5; ++k) if (lg[k] > best) { best = lg[k]; am = k; }
        out[320 + n] = (float)am;
        cls_i[n] = am;
    }
}

// ===================== bf16 MFMA decoder conv v2 (dec2/3) ==================
template<int CI,int CO,int HO,int NW>
__global__ __launch_bounds__(NW*64, 2)
void dec_conv_v2(const unsigned short* __restrict__ in,
                 const unsigned short* __restrict__ WT,
                 const float* __restrict__ Be,
                 const int* __restrict__ cls_i,
                 unsigned short* __restrict__ out)
{
    constexpr int HI = HO/2;
    constexpr int R = 6, C = 6;
    constexpr int CK = 64, CKQ = CK/32;
    constexpr int PITCH = CK + 8;
    constexpr int NTHR = NW*64;
    constexpr int NST = 9*CKQ;

    __shared__ __align__(16) unsigned short ilds[R*C*PITCH];

    const int n = blockIdx.z;
    const int e = cls_i[n];
    const int co0 = blockIdx.y * (NW*64);
    constexpr int TILES_X = HO/8;
    const int ty = blockIdx.x / TILES_X, tx = blockIdx.x % TILES_X;
    const int oh0 = ty*8, ow0 = tx*8;
    const int ih0 = oh0/2 - 1, iw0 = ow0/2 - 1;

    const int t = threadIdx.x;
    const int w = t >> 6, lane = t & 63;
    const int s = lane & 15, q = lane >> 4;

    const unsigned short* Wbase = WT + (long)e*CO*9*CI;
    const unsigned short* inN   = in + (long)n*HI*HI*CI;

    int dyy[4], dxx[4];
    #pragma unroll
    for (int si = 0; si < 4; ++si) { dyy[si] = si*2 + (s>>3); dxx[si] = s & 7; }

    long wrow[4];
    #pragma unroll
    for (int tn = 0; tn < 4; ++tn)
        wrow[tn] = (long)(co0 + w*64 + tn*16 + s)*9*CI + q*8;

    f32x4 acc[4][4];
    #pragma unroll
    for (int si = 0; si < 4; ++si)
        #pragma unroll
        for (int tn = 0; tn < 4; ++tn)
            acc[si][tn] = (f32x4){0.f,0.f,0.f,0.f};

    for (int ci0 = 0; ci0 < CI; ci0 += CK) {
        for (int i8 = t; i8 < R*C*8; i8 += NTHR) {
            int pix = i8 >> 3, cs = i8 & 7;
            int r = pix / C, c = pix % C;
            int ih = ih0 + r, iw = iw0 + c;
            uint4 v = {0u,0u,0u,0u};
            if (ih >= 0 && ih < HI && iw >= 0 && iw < HI)
                v = *reinterpret_cast<const uint4*>(&inN[((long)ih*HI + iw)*CI + ci0 + cs*8]);
            *reinterpret_cast<uint4*>(&ilds[pix*PITCH + cs*8]) = v;
        }
        __syncthreads();

        bf16x8 a[3][4];
        #pragma unroll
        for (int pf = 0; pf < 3; ++pf) {
            const int kp = pf/CKQ, cp = pf%CKQ;
            #pragma unroll
            for (int tn = 0; tn < 4; ++tn)
                a[pf][tn] = *reinterpret_cast<const bf16x8*>(&Wbase[wrow[tn] + kp*CI + ci0 + cp*32]);
        }
        #pragma unroll
        for (int st = 0; st < NST; ++st) {
            const int slot = st % 3;
            bf16x8 acur[4];
            #pragma unroll
            for (int tn = 0; tn < 4; ++tn) acur[tn] = a[slot][tn];
            if (st + 3 < NST) {
                const int kp = (st+3)/CKQ, cp = (st+3)%CKQ;
                #pragma unroll
                for (int tn = 0; tn < 4; ++tn)
                    a[slot][tn] = *reinterpret_cast<const bf16x8*>(&Wbase[wrow[tn] + kp*CI + ci0 + cp*32]);
            }
            const int k = st/CKQ, ckq = st%CKQ;
            const int kh = k/3, kw = k%3;
            #pragma unroll
            for (int si = 0; si < 4; ++si) {
                const int ihr = ((dyy[si] + kh - 1) >> 1) + 1;
                const int iwr = ((dxx[si] + kw - 1) >> 1) + 1;
                bf16x8 b = *reinterpret_cast<const bf16x8*>(
                    &ilds[(ihr*C + iwr)*PITCH + ckq*32 + q*8]);
                #pragma unroll
                for (int tn = 0; tn < 4; ++tn)
                    acc[si][tn] = __builtin_amdgcn_mfma_f32_16x16x32_bf16(acur[tn], b, acc[si][tn], 0, 0, 0);
            }
        }
        __syncthreads();
    }

    #pragma unroll
    for (int si = 0; si < 4; ++si) {
        int oh = oh0 + dyy[si], ow = ow0 + dxx[si];
        #pragma unroll
        for (int tn = 0; tn < 4; ++tn) {
            int co_b = co0 + w*64 + tn*16 + q*4;
            ushort4 st4;
            #pragma unroll
            for (int r = 0; r < 4; ++r) {
                float v = acc[si][tn][r] + Be[e*CO + co_b + r];
                v = fmaxf(v, 0.f);
                ((unsigned short*)&st4)[r] = f2bf(v);
            }
            *reinterpret_cast<ushort4*>(&out[(((long)n*HO + oh)*HO + ow)*CO + co_b]) = st4;
        }
    }
}

// ===================== bf16 MFMA decoder conv (dec4) =======================
template<int CI,int CO,int HO,int TH,int TW,int CO_T,int CK>
__global__ __launch_bounds__(256, 2)
void dec_conv_kernel(const unsigned short* __restrict__ in,
                     const unsigned short* __restrict__ WT,
                     const float* __restrict__ Be,
                     const int* __restrict__ cls_i,
                     unsigned short* __restrict__ out)
{
    constexpr int HI = HO/2;
    constexpr int R = TH/2 + 2, C = TW/2 + 2;
    constexpr int PITCH = CK + 8;
    constexpr int NT = CO_T/16;
    constexpr int S  = (TH*TW)/64;
    constexpr int SXT = TW/8;
    constexpr int CKQ = CK/32;
    constexpr int NST = 9*CKQ;

    __shared__ __align__(16) unsigned short ilds[R*C*PITCH];

    const int n = blockIdx.z;
    const int e = cls_i[n];
    const int co0 = blockIdx.y * CO_T;
    constexpr int TILES_X = HO/TW;
    const int ty = blockIdx.x / TILES_X, tx = blockIdx.x % TILES_X;
    const int oh0 = ty*TH, ow0 = tx*TW;
    const int ih0 = oh0/2 - 1, iw0 = ow0/2 - 1;

    const int t = threadIdx.x;
    const int w = t >> 6;
    const int lane = t & 63;
    const int s = lane & 15;
    const int q = lane >> 4;

    const unsigned short* Wbase = WT + ((long)e*CO + co0)*9*CI;
    const unsigned short* inN   = in + (long)n*HI*HI*CI;

    long wrow[NT];
    #pragma unroll
    for (int tn = 0; tn < NT; ++tn)
        wrow[tn] = (long)(tn*16 + s)*9*CI + q*8;

    f32x4 acc[S][NT];
    #pragma unroll
    for (int si = 0; si < S; ++si)
        #pragma unroll
        for (int tn = 0; tn < NT; ++tn)
            acc[si][tn] = (f32x4){0.f,0.f,0.f,0.f};

    int dy[S], dx[S];
    #pragma unroll
    for (int si = 0; si < S; ++si) {
        int sub = w + si*4;
        int sy = sub / SXT, sx = sub % SXT;
        dy[si] = sy*2 + (s >> 3);
        dx[si] = sx*8 + (s & 7);
    }

    for (int ci0 = 0; ci0 < CI; ci0 += CK) {
        constexpr int C8 = CK/8;
        for (int i8 = t; i8 < R*C*C8; i8 += 256) {
            int pix = i8 / C8, cs = i8 % C8;
            int r = pix / C, c = pix % C;
            int ih = ih0 + r, iw = iw0 + c;
            uint4 v = {0u,0u,0u,0u};
            if (ih >= 0 && ih < HI && iw >= 0 && iw < HI)
                v = *reinterpret_cast<const uint4*>(&inN[((long)ih*HI + iw)*CI + ci0 + cs*8]);
            *reinterpret_cast<uint4*>(&ilds[pix*PITCH + cs*8]) = v;
        }
        __syncthreads();

        bf16x8 a[3][NT];
        #pragma unroll
        for (int pf = 0; pf < 3 && pf < NST; ++pf) {
            const int kp = pf/CKQ, cp = pf%CKQ;
            #pragma unroll
            for (int tn = 0; tn < NT; ++tn)
                a[pf][tn] = *reinterpret_cast<const bf16x8*>(&Wbase[wrow[tn] + kp*CI + ci0 + cp*32]);
        }
        #pragma unroll
        for (int st = 0; st < NST; ++st) {
            const int slot = st % 3;
            bf16x8 acur[NT];
            #pragma unroll
            for (int tn = 0; tn < NT; ++tn) acur[tn] = a[slot][tn];
            if (st + 3 < NST) {
                const int kp = (st+3)/CKQ, cp = (st+3)%CKQ;
                #pragma unroll
                for (int tn = 0; tn < NT; ++tn)
                    a[slot][tn] = *reinterpret_cast<const bf16x8*>(&Wbase[wrow[tn] + kp*CI + ci0 + cp*32]);
            }
            const int k = st/CKQ, ckq = st%CKQ;
            const int kh = k/3, kw = k%3;
            #pragma unroll
            for (int si = 0; si < S; ++si) {
                int ihr = ((dy[si] + kh - 1) >> 1) + 1;
                int iwr = ((dx[si] + kw - 1) >> 1) + 1;
                bf16x8 b = *reinterpret_cast<const bf16x8*>(
                    &ilds[(ihr*C + iwr)*PITCH + ckq*32 + q*8]);
                #pragma unroll
                for (int tn = 0; tn < NT; ++tn)
                    acc[si][tn] = __builtin_amdgcn_mfma_f32_16x16x32_bf16(acur[tn], b, acc[si][tn], 0, 0, 0);
            }
        }
        __syncthreads();
    }

    #pragma unroll
    for (int si = 0; si < S; ++si) {
        int oh = oh0 + dy[si], ow = ow0 + dx[si];
        #pragma unroll
        for (int tn = 0; tn < NT; ++tn) {
            int co_b = co0 + tn*16 + q*4;
            ushort4 st4;
            #pragma unroll
            for (int r = 0; r < 4; ++r) {
                float v = acc[si][tn][r] + Be[e*CO + co_b + r];
                v = fmaxf(v, 0.f);
                ((unsigned short*)&st4)[r] = f2bf(v);
            }
            *reinterpret_cast<ushort4*>(&out[(((long)n*HO + oh)*HO + ow)*CO + co_b]) = st4;
        }
    }
}

// ===================== dec5 + 1x1 head fused ===============================
// in: dec4 out NHWC bf16 [64][64][64][32]; computes dec5 (up2+conv3x3+relu,
// CO=16) in accumulators, then applies 1x1 head (5ch) via cross-lane
// reduction over the 4 q-lanes; writes seg fp32 NCHW directly.
__global__ __launch_bounds__(256, 2)
void dec5_head_kernel(const unsigned short* __restrict__ in,
                      const unsigned short* __restrict__ WT,   // [5][16][9][32]
                      const float* __restrict__ be5,           // [5][16]
                      const float* __restrict__ We6,           // [5][5*16]
                      const float* __restrict__ be6,           // [5][5]
                      const int* __restrict__ cls_i,
                      float* __restrict__ seg)
{
    constexpr int CI = 32, CO = 16, HO = 128, TH = 16, TW = 32, CK = 32;
    constexpr int HI = 64, R = TH/2 + 2, C = TW/2 + 2, PITCH = CK + 8;
    constexpr int S = (TH*TW)/64, SXT = TW/8;
    constexpr int NST = 9;

    __shared__ __align__(16) unsigned short ilds[R*C*PITCH];
    __shared__ float hw[85];

    const int n = blockIdx.z;
    const int e = cls_i[n];
    constexpr int TILES_X = HO/TW;   // 4
    const int ty = blockIdx.x / TILES_X, tx = blockIdx.x % TILES_X;
    const int oh0 = ty*TH, ow0 = tx*TW;
    const int ih0 = oh0/2 - 1, iw0 = ow0/2 - 1;

    const int t = threadIdx.x;
    const int w = t >> 6, lane = t & 63;
    const int s = lane & 15, q = lane >> 4;

    if (t < 80) hw[t] = We6[(long)e*80 + t];
    if (t < 5)  hw[80+t] = be6[e*5 + t];

    const unsigned short* Wbase = WT + (long)e*CO*9*CI;
    const unsigned short* inN   = in + (long)n*HI*HI*CI;

    long wrow = (long)s*9*CI + q*8;   // NT=1, co row = s

    f32x4 acc[S];
    #pragma unroll
    for (int si = 0; si < S; ++si) acc[si] = (f32x4){0.f,0.f,0.f,0.f};

    int dy[S], dx[S];
    #pragma unroll
    for (int si = 0; si < S; ++si) {
        int sub = w + si*4;
        int sy = sub / SXT, sx = sub % SXT;
        dy[si] = sy*2 + (s >> 3);
        dx[si] = sx*8 + (s & 7);
    }

    // single ci chunk (CI == CK == 32)
    {
        constexpr int C8 = CK/8;
        for (int i8 = t; i8 < R*C*C8; i8 += 256) {
            int pix = i8 / C8, cs = i8 % C8;
            int r = pix / C, c = pix % C;
            int ih = ih0 + r, iw = iw0 + c;
            uint4 v = {0u,0u,0u,0u};
            if (ih >= 0 && ih < HI && iw >= 0 && iw < HI)
                v = *reinterpret_cast<const uint4*>(&inN[((long)ih*HI + iw)*CI + cs*8]);
            *reinterpret_cast<uint4*>(&ilds[pix*PITCH + cs*8]) = v;
        }
        __syncthreads();

        bf16x8 a[3];
        #pragma unroll
        for (int pf = 0; pf < 3; ++pf)
            a[pf] = *reinterpret_cast<const bf16x8*>(&Wbase[wrow + pf*CI]);
        #pragma unroll
        for (int st = 0; st < NST; ++st) {
            const int slot = st % 3;
            bf16x8 acur = a[slot];
            if (st + 3 < NST)
                a[slot] = *reinterpret_cast<const bf16x8*>(&Wbase[wrow + (st+3)*CI]);
            const int kh = st/3, kw = st%3;
            #pragma unroll
            for (int si = 0; si < S; ++si) {
                int ihr = ((dy[si] + kh - 1) >> 1) + 1;
                int iwr = ((dx[si] + kw - 1) >> 1) + 1;
                bf16x8 b = *reinterpret_cast<const bf16x8*>(
                    &ilds[(ihr*C + iwr)*PITCH + q*8]);
                acc[si] = __builtin_amdgcn_mfma_f32_16x16x32_bf16(acur, b, acc[si], 0, 0, 0);
            }
        }
    }

    // epilogue: dec5 bias+relu (fp32), 1x1 head, q-lane reduce, fp32 store
    #pragma unroll
    for (int si = 0; si < S; ++si) {
        float v[4];
        #pragma unroll
        for (int r = 0; r < 4; ++r)
            v[r] = fmaxf(acc[si][r] + be5[e*16 + q*4 + r], 0.f);
        float part[5];
        #pragma unroll
        for (int c = 0; c < 5; ++c)
            part[c] = v[0]*hw[c*16 + q*4] + v[1]*hw[c*16 + q*4 + 1]
                    + v[2]*hw[c*16 + q*4 + 2] + v[3]*hw[c*16 + q*4 + 3];
        #pragma unroll
        for (int c = 0; c < 5; ++c) {
            part[c] += __shfl_xor(part[c], 16, 64);
            part[c] += __shfl_xor(part[c], 32, 64);
        }
        if (q == 0) {
            int oh = oh0 + dy[si], ow = ow0 + dx[si];
            #pragma unroll
            for (int c = 0; c < 5; ++c)
                seg[(((long)n*5 + c)*128 + oh)*128 + ow] = part[c] + hw[80+c];
        }
    }
}

// ===========================================================================
extern "C" void kernel_launch(void* const* d_in, const int* in_sizes, int n_in,
                              void* d_out, int out_size, void* d_ws, size_t ws_size,
                              hipStream_t stream)
{
    const float* x   = (const float*)d_in[0];
    const float* Wb1 = (const float*)d_in[1];  const float* bb1 = (const float*)d_in[2];
    const float* Wb2 = (const float*)d_in[3];  const float* bb2 = (const float*)d_in[4];
    const float* Wb3 = (const float*)d_in[5];  const float* bb3 = (const float*)d_in[6];
    const float* Wb4 = (const float*)d_in[7];  const float* bb4 = (const float*)d_in[8];
    const float* Wb5 = (const float*)d_in[9];  const float* bb5 = (const float*)d_in[10];
    const float* Wc1 = (const float*)d_in[11]; const float* bc1 = (const float*)d_in[12];
    const float* Wc2 = (const float*)d_in[13]; const float* bc2 = (const float*)d_in[14];
    const float* We1 = (const float*)d_in[15]; const float* be1 = (const float*)d_in[16];
    const float* We2 = (const float*)d_in[17]; const float* be2 = (const float*)d_in[18];
    const float* We3 = (const float*)d_in[19]; const float* be3 = (const float*)d_in[20];
    const float* We4 = (const float*)d_in[21]; const float* be4 = (const float*)d_in[22];
    const float* We5 = (const float*)d_in[23]; const float* be5 = (const float*)d_in[24];
    const float* We6 = (const float*)d_in[25]; const float* be6 = (const float*)d_in[26];

    float* out = (float*)d_out;
    char* ws = (char*)d_ws;

    // ---- X region (67 MB): H1 -> {H3, WB4/5} -> SKBUF5 -> {Q/DBUF1, WT1-5}
    unsigned short* H1hi = (unsigned short*)(ws + 0);
    unsigned short* H1lo = (unsigned short*)(ws + 33554432);
    unsigned short* H3hi = (unsigned short*)(ws + 0);
    unsigned short* H3lo = (unsigned short*)(ws + 8388608);
    unsigned short* WB4hi = (unsigned short*)(ws + 16777216);
    unsigned short* WB4lo = (unsigned short*)(ws + 19136512);
    unsigned short* WB5hi = (unsigned short*)(ws + 21495808);
    unsigned short* WB5lo = (unsigned short*)(ws + 26214400);
    float*          SKBUF5 = (float*)(ws + 0);
    unsigned short* P    = (unsigned short*)(ws + 0);
    unsigned short* Q    = (unsigned short*)(ws + 33554432);
    float*          DBUF1 = (float*)(ws + 33554432);
    unsigned short* WT1  = (unsigned short*)(ws + 50331648);
    unsigned short* WT2  = (unsigned short*)(ws + 62128128);
    unsigned short* WT3  = (unsigned short*)(ws + 65077248);
    unsigned short* WT4  = (unsigned short*)(ws + 65814528);
    unsigned short* WT5  = (unsigned short*)(ws + 65998848);

    // ---- Y region (33.5 MB): H2 -> {H4, FEATS, cls} ----
    char* Y = ws + 67108864;
    unsigned short* H2hi = (unsigned short*)(Y + 0);
    unsigned short* H2lo = (unsigned short*)(Y + 16777216);
    unsigned short* H4hi = (unsigned short*)(Y + 0);
    unsigned short* H4lo = (unsigned short*)(Y + 4194304);
    unsigned short* FShi = (unsigned short*)(Y + 8388608);
    unsigned short* FSlo = (unsigned short*)(Y + 9437184);
    int*   cls_i  = (int*)(Y + 10649600);

    // ---- W23 tail (1.5 MB) ----
    char* W23 = ws + 100663296;
    unsigned short* WB2hi = (unsigned short*)(W23 + 0);
    unsigned short* WB2lo = (unsigned short*)(W23 + 147456);
    unsigned short* WB3hi = (unsigned short*)(W23 + 294912);
    unsigned short* WB3lo = (unsigned short*)(W23 + 884736);

    // ---- early transposes (WB2+WB3 fused) ----
    hipLaunchKernelGGL(early_trans_kernel, dim3(384), dim3(256), 0, stream,
                       Wb2, Wb3, WB2hi, WB2lo, WB3hi, WB3lo);

    // ---- conv1 ----
    hipLaunchKernelGGL(conv1_kernel, dim3(64,2,64), dim3(256), 0, stream, x, Wb1, bb1, H1hi, H1lo);

    // ---- conv2 (R6 structure) ----
    hipLaunchKernelGGL((bb_conv_v2<64,128,32,2,1>), dim3(16,1,64), dim3(128), 0, stream,
                       H1hi, H1lo, WB2hi, WB2lo, bb2, H2hi, H2lo);

    // ---- H1 dead: all remaining transposes in one launch ----
    hipLaunchKernelGGL(late_trans_kernel, dim3(3504), dim3(256), 0, stream,
                       Wb4, Wb5, We1, We2, We3, We4, We5,
                       WB4hi, WB4lo, WB5hi, WB5lo, WT1, WT2, WT3, WT4, WT5);

    // ---- conv3/conv4 (R6 structure) ----
    hipLaunchKernelGGL((bb_conv_v2<128,256,16,2,1>), dim3(4,2,64), dim3(128), 0, stream,
                       H2hi, H2lo, WB3hi, WB3lo, bb3, H3hi, H3lo);
    hipLaunchKernelGGL((bb_conv_v2<256,512, 8,2,1>), dim3(1,4,64), dim3(128), 0, stream,
                       H3hi, H3lo, WB4hi, WB4lo, bb4, H4hi, H4lo);

    // ---- conv5: split-K partials + reduce ----
    hipLaunchKernelGGL(conv5_partial, dim3(8,4,16), dim3(128), 0, stream,
                       H4hi, H4lo, WB5hi, WB5lo, SKBUF5);
    hipLaunchKernelGGL(conv5_reduce, dim3(2048), dim3(256), 0, stream,
                       SKBUF5, bb5, FShi, FSlo);

    // ---- classifier ----
    hipLaunchKernelGGL(classifier_kernel, dim3(64), dim3(128), 0, stream,
                       FShi, FSlo, Wc1, bc1, Wc2, bc2, out, cls_i);

    // ---- dec1: split-K partials + reduce -> P ----
    hipLaunchKernelGGL(dec1_partial, dim3(4,2,64), dim3(128), 0, stream,
                       FShi, WT1, cls_i, DBUF1);
    hipLaunchKernelGGL(dec1_reduce, dim3(4096), dim3(256), 0, stream,
                       DBUF1, be1, cls_i, P);

    // ---- dec2..4: P -> Q -> P -> Q ----
    hipLaunchKernelGGL((dec_conv_v2<256,128, 16,2>), dim3(4, 1,64), dim3(128), 0, stream, P, WT2, be2, cls_i, Q);
    hipLaunchKernelGGL((dec_conv_v2<128, 64, 32,1>), dim3(16,1,64), dim3(64),  0, stream, Q, WT3, be3, cls_i, P);
    hipLaunchKernelGGL((dec_conv_kernel< 64, 32, 64, 16,16, 32,64>), dim3(16, 1,64), dim3(256), 0, stream, P, WT4, be4, cls_i, Q);

    // ---- dec5 + 1x1 head fused -> seg (NCHW fp32) ----
    hipLaunchKernelGGL(dec5_head_kernel, dim3(32,1,64), dim3(256), 0, stream,
                       Q, WT5, be5, We6, be6, cls_i, out + 384);
}